// Round 1
// baseline (70.244 us; speedup 1.0000x reference)
//
#include <hip/hip_runtime.h>
#include <hip/hip_bf16.h>

#define B_ 2048
#define L_ 512
#define D_ 17
#define H_ 8
#define HID_ 256
#define SPECIAL_ 9
#define OUT_ 23
#define XROW (513*17)   /* 8721 floats per batch row of x */
#define SEQN (512*17)   /* 8704 floats of seq per batch */

// ---------------- Kernel 1: streaming attention -> comb (B x 26) ----------------
__global__ __launch_bounds__(256) void attn_comb_kernel(
    const float* __restrict__ x,
    const float* __restrict__ Wk, const float* __restrict__ bk,
    const float* __restrict__ Wv, const float* __restrict__ bv,
    const float* __restrict__ q,
    const float* __restrict__ Wo, const float* __restrict__ bo,
    float* __restrict__ comb)
{
  __shared__ __align__(16) float s_seq[SEQN];   // reused as partial buffer later
  __shared__ float s_qk[H_][D_];
  __shared__ float s_c[H_];
  __shared__ float s_swn[H_][D_ + 1];
  __shared__ float s_agg[H_ * D_];

  const int t = threadIdx.x;
  const int b = blockIdx.x;
  const float* xb = x + (size_t)b * XROW;

  // stage seq rows (coalesced scalar loads)
  for (int i = t; i < SEQN; i += 256) s_seq[i] = xb[D_ + i];

  // fold q into Wk:  qk[h][d] = sum_e Wk[h,e,d] * q[h,e];  c[h] = bk[h]·q[h]
  if (t < H_ * D_) {
    int h = t / D_, dd = t - h * D_;
    float s = 0.f;
    #pragma unroll
    for (int e = 0; e < D_; ++e) s += Wk[h * D_ * D_ + e * D_ + dd] * q[h * D_ + e];
    s_qk[h][dd] = s;
  }
  if (t < H_) {
    float s = 0.f;
    #pragma unroll
    for (int e = 0; e < D_; ++e) s += bk[t * D_ + e] * q[t * D_ + e];
    s_c[t] = s;
  }
  __syncthreads();

  const int h = t & (H_ - 1);   // head
  const int chunk = t >> 3;     // 0..31, rows chunk + 32*r

  float qk[D_];
  #pragma unroll
  for (int d = 0; d < D_; ++d) qk[d] = s_qk[h][d];
  const float ch = s_c[h];

  float m = -INFINITY, den = 0.f;
  float acc[D_];
  #pragma unroll
  for (int d = 0; d < D_; ++d) acc[d] = 0.f;

  for (int r = 0; r < 16; ++r) {
    const float* row = &s_seq[(chunk + (r << 5)) * D_];
    float rv[D_];
    float sab = 0.f, sc = ch;
    #pragma unroll
    for (int d = 0; d < D_; ++d) {
      float v = row[d]; rv[d] = v;
      sab += fabsf(v);
      sc = fmaf(qk[d], v, sc);
    }
    if (sab == 0.f) continue;   // masked row (exact zeros), matches reference mask
    if (sc <= m) {
      float p = __expf(sc - m);
      den += p;
      #pragma unroll
      for (int d = 0; d < D_; ++d) acc[d] = fmaf(p, rv[d], acc[d]);
    } else {
      float f = (m == -INFINITY) ? 0.f : __expf(m - sc);
      den = fmaf(den, f, 1.f);
      #pragma unroll
      for (int d = 0; d < D_; ++d) acc[d] = fmaf(acc[d], f, rv[d]);
      m = sc;
    }
  }

  __syncthreads();              // everyone done reading s_seq; reuse as partials
  float* ps = s_seq;            // layout: [256][19] = m, den, acc[17]
  {
    float* p0 = &ps[t * 19];
    p0[0] = m; p0[1] = den;
    #pragma unroll
    for (int d = 0; d < D_; ++d) p0[2 + d] = acc[d];
  }
  // tree-combine over the 32 chunks (slot index = chunk*8 + h)
  for (int off = 128; off >= 8; off >>= 1) {
    __syncthreads();
    if (t < off) {
      float* pa = &ps[t * 19];
      const float* pb = &ps[(t + off) * 19];
      float ma = pa[0], mb = pb[0];
      if (mb != -INFINITY) {
        if (ma == -INFINITY) {
          pa[0] = mb; pa[1] = pb[1];
          #pragma unroll
          for (int d = 0; d < D_; ++d) pa[2 + d] = pb[2 + d];
        } else {
          float M = fmaxf(ma, mb);
          float fa = __expf(ma - M), fb = __expf(mb - M);
          pa[0] = M;
          pa[1] = pa[1] * fa + pb[1] * fb;
          #pragma unroll
          for (int d = 0; d < D_; ++d) pa[2 + d] = pa[2 + d] * fa + pb[2 + d] * fb;
        }
      }
    }
  }
  __syncthreads();
  if (t < H_) {
    const float* pf = &ps[t * 19];
    float inv = 1.f / pf[1];
    #pragma unroll
    for (int d = 0; d < D_; ++d) s_swn[t][d] = pf[2 + d] * inv;
  }
  __syncthreads();
  // agg[h,e] = bv[h,e] + Wv[h,e,:]·swn[h,:]
  if (t < H_ * D_) {
    int hh = t / D_, e = t - hh * D_;
    float s = bv[hh * D_ + e];
    #pragma unroll
    for (int d = 0; d < D_; ++d) s = fmaf(Wv[hh * D_ * D_ + e * D_ + d], s_swn[hh][d], s);
    s_agg[hh * D_ + e] = s;
  }
  __syncthreads();
  // attn[j] = bo[j] + Wo[j,:]·agg ; comb = [attn(17) | special(9)]
  if (t < D_) {
    float s = bo[t];
    for (int k = 0; k < H_ * D_; ++k) s = fmaf(Wo[t * H_ * D_ + k], s_agg[k], s);
    comb[b * 26 + t] = s;
  } else if (t < 26) {
    comb[b * 26 + t] = xb[t - D_];   // special = x[b, 0, 0..8]
  }
}

// ---------------- Kernel 2: transpose the two 256x256 weight matrices ----------------
__global__ __launch_bounds__(256) void transpose_w2_kernel(
    const float* __restrict__ pW2, const float* __restrict__ vW2,
    float* __restrict__ pW2t, float* __restrict__ vW2t)
{
  int idx = blockIdx.x * 256 + threadIdx.x;   // 0..65535
  int k = idx >> 8, i = idx & 255;
  pW2t[idx] = pW2[i * HID_ + k];
  vW2t[idx] = vW2[i * HID_ + k];
}

// ---------------- Kernel 3: fused policy+value MLPs ----------------
// 512 threads: t<256 -> policy MLP, t>=256 -> value MLP. 8 batches per block.
__global__ __launch_bounds__(512) void mlp_kernel(
    const float* __restrict__ comb,
    const float* __restrict__ pW1, const float* __restrict__ pb1,
    const float* __restrict__ pW2t, const float* __restrict__ pb2,
    const float* __restrict__ pW3, const float* __restrict__ pb3,
    const float* __restrict__ vW1, const float* __restrict__ vb1,
    const float* __restrict__ vW2t, const float* __restrict__ vb2,
    const float* __restrict__ vW3, const float* __restrict__ vb3,
    float* __restrict__ out)
{
  __shared__ __align__(16) float s_comb[26][8];
  __shared__ __align__(16) float s_h1[2][HID_][8];
  __shared__ __align__(16) float s_h2[2][HID_][8];

  const int t = threadIdx.x;
  const int b0 = blockIdx.x * 8;
  const int p = t >> 8;       // 0 = policy, 1 = value
  const int i = t & 255;

  if (t < 26 * 8) {
    int bb = t & 7, k = t >> 3;
    s_comb[k][bb] = comb[(size_t)(b0 + bb) * 26 + k];
  }
  __syncthreads();

  const float* W1 = p ? vW1 : pW1;
  const float* b1 = p ? vb1 : pb1;
  const float* W2t = p ? vW2t : pW2t;
  const float* b2 = p ? vb2 : pb2;

  // ---- layer 1: h1 = relu(W1 @ comb + b1), 26 -> 256
  {
    float4 a0 = {0,0,0,0}, a1 = {0,0,0,0};
    const float* w = W1 + i * 26;
    #pragma unroll
    for (int k = 0; k < 26; ++k) {
      float wk = w[k];
      const float4* hv = (const float4*)&s_comb[k][0];
      float4 x0 = hv[0], x1 = hv[1];
      a0.x = fmaf(wk, x0.x, a0.x); a0.y = fmaf(wk, x0.y, a0.y);
      a0.z = fmaf(wk, x0.z, a0.z); a0.w = fmaf(wk, x0.w, a0.w);
      a1.x = fmaf(wk, x1.x, a1.x); a1.y = fmaf(wk, x1.y, a1.y);
      a1.z = fmaf(wk, x1.z, a1.z); a1.w = fmaf(wk, x1.w, a1.w);
    }
    float bias = b1[i];
    float4 r0, r1;
    r0.x = fmaxf(a0.x + bias, 0.f); r0.y = fmaxf(a0.y + bias, 0.f);
    r0.z = fmaxf(a0.z + bias, 0.f); r0.w = fmaxf(a0.w + bias, 0.f);
    r1.x = fmaxf(a1.x + bias, 0.f); r1.y = fmaxf(a1.y + bias, 0.f);
    r1.z = fmaxf(a1.z + bias, 0.f); r1.w = fmaxf(a1.w + bias, 0.f);
    ((float4*)&s_h1[p][i][0])[0] = r0;
    ((float4*)&s_h1[p][i][0])[1] = r1;
  }
  __syncthreads();

  // ---- layer 2: h2 = relu(W2 @ h1 + b2), 256 -> 256 (coalesced transposed weights)
  {
    float4 a0 = {0,0,0,0}, a1 = {0,0,0,0};
    #pragma unroll 4
    for (int k = 0; k < HID_; ++k) {
      float wk = W2t[k * HID_ + i];
      const float4* hv = (const float4*)&s_h1[p][k][0];
      float4 x0 = hv[0], x1 = hv[1];
      a0.x = fmaf(wk, x0.x, a0.x); a0.y = fmaf(wk, x0.y, a0.y);
      a0.z = fmaf(wk, x0.z, a0.z); a0.w = fmaf(wk, x0.w, a0.w);
      a1.x = fmaf(wk, x1.x, a1.x); a1.y = fmaf(wk, x1.y, a1.y);
      a1.z = fmaf(wk, x1.z, a1.z); a1.w = fmaf(wk, x1.w, a1.w);
    }
    float bias = b2[i];
    float4 r0, r1;
    r0.x = fmaxf(a0.x + bias, 0.f); r0.y = fmaxf(a0.y + bias, 0.f);
    r0.z = fmaxf(a0.z + bias, 0.f); r0.w = fmaxf(a0.w + bias, 0.f);
    r1.x = fmaxf(a1.x + bias, 0.f); r1.y = fmaxf(a1.y + bias, 0.f);
    r1.z = fmaxf(a1.z + bias, 0.f); r1.w = fmaxf(a1.w + bias, 0.f);
    ((float4*)&s_h2[p][i][0])[0] = r0;
    ((float4*)&s_h2[p][i][0])[1] = r1;
  }
  __syncthreads();

  // ---- layer 3
  if (t < 184) {                       // policy head: 8 batches x 23 outputs
    int bb = t / 23, o = t - bb * 23;
    const float* w = pW3 + o * HID_;
    float s = pb3[o];
    for (int k = 0; k < HID_; ++k) s = fmaf(w[k], s_h2[0][k][bb], s);
    out[(size_t)(b0 + bb) * OUT_ + o] = s;
  } else if (p == 1 && i < 8) {        // value head: 8 batches x 1 output
    int bb = i;
    float s = vb3[0];
    for (int k = 0; k < HID_; ++k) s = fmaf(vW3[k], s_h2[1][k][bb], s);
    out[(size_t)B_ * OUT_ + b0 + bb] = s;
  }
}

extern "C" void kernel_launch(void* const* d_in, const int* in_sizes, int n_in,
                              void* d_out, int out_size, void* d_ws, size_t ws_size,
                              hipStream_t stream) {
  (void)in_sizes; (void)n_in; (void)out_size; (void)ws_size;
  const float* x   = (const float*)d_in[0];
  const float* Wk  = (const float*)d_in[1];
  const float* bk  = (const float*)d_in[2];
  const float* Wv  = (const float*)d_in[3];
  const float* bv  = (const float*)d_in[4];
  const float* q   = (const float*)d_in[5];
  const float* Wo  = (const float*)d_in[6];
  const float* bo  = (const float*)d_in[7];
  const float* pW1 = (const float*)d_in[8];
  const float* pb1 = (const float*)d_in[9];
  const float* pW2 = (const float*)d_in[10];
  const float* pb2 = (const float*)d_in[11];
  const float* pW3 = (const float*)d_in[12];
  const float* pb3 = (const float*)d_in[13];
  const float* vW1 = (const float*)d_in[14];
  const float* vb1 = (const float*)d_in[15];
  const float* vW2 = (const float*)d_in[16];
  const float* vb2 = (const float*)d_in[17];
  const float* vW3 = (const float*)d_in[18];
  const float* vb3 = (const float*)d_in[19];
  float* out = (float*)d_out;

  // workspace layout: comb (2048*26) | pW2t (65536) | vW2t (65536) floats
  float* comb  = (float*)d_ws;
  float* pW2t  = comb + (size_t)B_ * 26;
  float* vW2t  = pW2t + (size_t)HID_ * HID_;

  transpose_w2_kernel<<<HID_ * HID_ / 256, 256, 0, stream>>>(pW2, vW2, pW2t, vW2t);
  attn_comb_kernel<<<B_, 256, 0, stream>>>(x, Wk, bk, Wv, bv, q, Wo, bo, comb);
  mlp_kernel<<<B_ / 8, 512, 0, stream>>>(comb, pW1, pb1, pW2t, pb2, pW3, pb3,
                                         vW1, vb1, vW2t, vb2, vW3, vb3, out);
}